// Round 11
// baseline (1854.980 us; speedup 1.0000x reference)
//
#include <hip/hip_runtime.h>
#include <math.h>

#define NN 100000
#define EE 3200000
#define EPSL 0.01f
#define KB 391
#define NTILES 6250          // NN/16 exactly
#define GRIDT 1563           // ceil(6250/4)
#define DEC_OFF (13 * 4096)  // plane-buffer offset of decoder weights

typedef _Float16 half_t;
typedef __attribute__((ext_vector_type(8))) short short8;
typedef __attribute__((ext_vector_type(4))) float f32x4;

#define MFMAB(a, b, c) __builtin_amdgcn_mfma_f32_16x16x32_bf16(a, b, c, 0, 0, 0)

__device__ __forceinline__ short f2bfh(float f) {
    union { float f; unsigned u; } c; c.f = f;
    unsigned u = c.u + (0x7fffu + ((c.u >> 16) & 1u));
    return (short)(u >> 16);
}
__device__ __forceinline__ float bfh2f(short s) {
    union { unsigned u; float f; } c;
    c.u = ((unsigned)(unsigned short)s) << 16;
    return c.f;
}
// fp32 -> 3-term bf16 split (a = s1+s2+s3 with ~2^-24 residual)
__device__ __forceinline__ void split3(float f, short& s1, short& s2, short& s3) {
    s1 = f2bfh(f);
    float r = f - bfh2f(s1);
    s2 = f2bfh(r);
    r = r - bfh2f(s2);
    s3 = f2bfh(r);
}

// A-frags (3 planes) from row-major fp32: lane m=lane&15, quad=lane>>4
__device__ __forceinline__ void afrag6(const float* __restrict__ xb, int m, int quad,
                                       int hh, int stride, short8& a1, short8& a2, short8& a3) {
    const float* p = xb + m * stride + hh * 32 + quad * 8;
#pragma unroll
    for (int j = 0; j < 8; ++j) {
        short s1, s2, s3;
        split3(p[j], s1, s2, s3);
        a1[j] = s1; a2[j] = s2; a3[j] = s3;
    }
}

// B-frags from staged LDS: Whm = (s1<<16|s2) u32 stride 65, Wl = s3 u16 stride 65
__device__ __forceinline__ f32x4 gemm_tile6(const unsigned* Whm, const unsigned short* Wl,
                                            int t, int lane,
                                            const short8* a1, const short8* a2, const short8* a3,
                                            float bias) {
    f32x4 acc = {bias, bias, bias, bias};
    int n = t * 16 + (lane & 15);
    int q8 = (lane >> 4) * 8;
#pragma unroll
    for (int hh = 0; hh < 2; ++hh) {
        short8 bh, bm, bl;
        int k0 = hh * 32 + q8;
#pragma unroll
        for (int j = 0; j < 8; ++j) {
            unsigned u = Whm[(k0 + j) * 65 + n];
            bh[j] = (short)(u >> 16);
            bm[j] = (short)(u & 0xffffu);
            bl[j] = (short)Wl[(k0 + j) * 65 + n];
        }
        acc = MFMAB(a1[hh], bh, acc);
        acc = MFMAB(a1[hh], bm, acc);
        acc = MFMAB(a2[hh], bh, acc);
        acc = MFMAB(a1[hh], bl, acc);
        acc = MFMAB(a2[hh], bm, acc);
        acc = MFMAB(a3[hh], bh, acc);
    }
    return acc;
}
// stage pre-split planes (global, compact [k*64+n]) into padded LDS (stride 65)
__device__ __forceinline__ void stageP(const unsigned* __restrict__ g_hm,
                                       const unsigned short* __restrict__ g_l,
                                       unsigned* Whm, unsigned short* Wl) {
    for (int i = threadIdx.x; i < 4096; i += 256) {
        int k = i >> 6, n = i & 63;
        Whm[k * 65 + n] = g_hm[i];
        Wl[k * 65 + n] = g_l[i];
    }
}

// ================= weight pre-split (once per launch) =================
// slots: 0 enc | 1,2 lin | 3,4 diss | 5,6 forc | 7,8 vel | 9,10 mlp_w1 | 11,12 mlp_w2 | 13 dec(2048)

__global__ __launch_bounds__(256) void k_prep(const float* __restrict__ enc_w,
                                              const float* __restrict__ lin_w,
                                              const float* __restrict__ diss_w,
                                              const float* __restrict__ forc_w,
                                              const float* __restrict__ vel_w,
                                              const float* __restrict__ w1,
                                              const float* __restrict__ w2,
                                              const float* __restrict__ dec_w,
                                              unsigned* __restrict__ Whm,
                                              unsigned short* __restrict__ Wl) {
    int slot = blockIdx.x;
    const float* src;
    int size = 4096;
    int off = slot * 4096;
    switch (slot) {
        case 0:  src = enc_w; break;
        case 1:  case 2:  src = lin_w  + (slot - 1)  * 4096; break;
        case 3:  case 4:  src = diss_w + (slot - 3)  * 4096; break;
        case 5:  case 6:  src = forc_w + (slot - 5)  * 4096; break;
        case 7:  case 8:  src = vel_w  + (slot - 7)  * 4096; break;
        case 9:  case 10: src = w1     + (slot - 9)  * 4096; break;
        case 11: case 12: src = w2     + (slot - 11) * 4096; break;
        default: src = dec_w; size = 2048; break;
    }
    for (int i = threadIdx.x; i < size; i += 256) {
        short s1, s2, s3;
        split3(src[i], s1, s2, s3);
        Whm[off + i] = (((unsigned)(unsigned short)s1) << 16) | (unsigned)(unsigned short)s2;
        Wl[off + i] = (unsigned short)s3;
    }
}

// ================= CSR build (unchanged) =================

__global__ __launch_bounds__(256) void k_hist2(const int* __restrict__ row,
                                               const int* __restrict__ col,
                                               int* __restrict__ bc_row,
                                               int* __restrict__ bc_col, int e) {
    __shared__ int hr[KB], hc[KB];
    for (int i = threadIdx.x; i < KB; i += 256) { hr[i] = 0; hc[i] = 0; }
    __syncthreads();
    for (int i = blockIdx.x * 256 + threadIdx.x; i < e; i += gridDim.x * 256) {
        atomicAdd(&hr[row[i] >> 8], 1);
        atomicAdd(&hc[col[i] >> 8], 1);
    }
    __syncthreads();
    for (int i = threadIdx.x; i < KB; i += 256) {
        if (hr[i]) atomicAdd(&bc_row[i], hr[i]);
        if (hc[i]) atomicAdd(&bc_col[i], hc[i]);
    }
}

__global__ __launch_bounds__(512) void k_scan_buckets(const int* __restrict__ bc_col,
                                                      const int* __restrict__ bc_row,
                                                      int* __restrict__ bs_col,
                                                      int* __restrict__ bs_row,
                                                      int* __restrict__ cur_col,
                                                      int* __restrict__ cur_row) {
    __shared__ int s[512];
    int i = threadIdx.x;
    int v = (i < KB) ? bc_col[i] : 0;
    s[i] = v; __syncthreads();
    for (int off = 1; off < 512; off <<= 1) {
        int t = (i >= off) ? s[i - off] : 0;
        __syncthreads(); s[i] += t; __syncthreads();
    }
    if (i < KB) { int ex = s[i] - v; bs_col[i] = ex; cur_col[i] = ex; }
    if (i == 511) bs_col[KB] = s[511];
    __syncthreads();
    v = (i < KB) ? bc_row[i] : 0;
    s[i] = v; __syncthreads();
    for (int off = 1; off < 512; off <<= 1) {
        int t = (i >= off) ? s[i - off] : 0;
        __syncthreads(); s[i] += t; __syncthreads();
    }
    if (i < KB) { int ex = s[i] - v; bs_row[i] = ex; cur_row[i] = ex; }
    if (i == 511) bs_row[KB] = s[511];
}

__global__ __launch_bounds__(256) void k_bucket_scatter(const int* __restrict__ keys,
                                                        const int* __restrict__ vals,
                                                        int* __restrict__ cursors,
                                                        uint2* __restrict__ tmp, int e) {
    __shared__ int lcnt[KB];
    __shared__ int lbase[KB];
    for (int i = threadIdx.x; i < KB; i += 256) lcnt[i] = 0;
    __syncthreads();
    int tile = blockIdx.x * 2048;
    int kv[8], vv[8], rk[8];
#pragma unroll
    for (int u = 0; u < 8; ++u) {
        int i = tile + u * 256 + threadIdx.x;
        if (i < e) {
            kv[u] = keys[i];
            vv[u] = vals[i];
            rk[u] = atomicAdd(&lcnt[kv[u] >> 8], 1);
        } else kv[u] = -1;
    }
    __syncthreads();
    for (int i = threadIdx.x; i < KB; i += 256) {
        int c = lcnt[i];
        if (c) lbase[i] = atomicAdd(&cursors[i], c);
    }
    __syncthreads();
#pragma unroll
    for (int u = 0; u < 8; ++u) {
        if (kv[u] >= 0)
            tmp[lbase[kv[u] >> 8] + rk[u]] = make_uint2((unsigned)vv[u], (unsigned)kv[u]);
    }
}

__global__ __launch_bounds__(256) void k_bucket_finalize(const uint2* __restrict__ tmp,
                                                         const int* __restrict__ bstarts,
                                                         int* __restrict__ starts_out,
                                                         int* __restrict__ idx_out, int n) {
    __shared__ int hist[256], cur[256], ss[256];
    int b = blockIdx.x;
    int base_node = b << 8;
    int e0 = bstarts[b], e1 = bstarts[b + 1];
    hist[threadIdx.x] = 0;
    __syncthreads();
    for (int i = e0 + (int)threadIdx.x; i < e1; i += 256)
        atomicAdd(&hist[(int)tmp[i].y - base_node], 1);
    __syncthreads();
    int v = hist[threadIdx.x];
    ss[threadIdx.x] = v; __syncthreads();
    for (int off = 1; off < 256; off <<= 1) {
        int t = (threadIdx.x >= (unsigned)off) ? ss[threadIdx.x - off] : 0;
        __syncthreads(); ss[threadIdx.x] += t; __syncthreads();
    }
    int excl = ss[threadIdx.x] - v;
    int node = base_node + (int)threadIdx.x;
    if (node < n) starts_out[node] = e0 + excl;
    if (b == (int)gridDim.x - 1 && threadIdx.x == 0) starts_out[n] = e1;
    cur[threadIdx.x] = excl;
    __syncthreads();
    for (int i = e0 + (int)threadIdx.x; i < e1; i += 256) {
        uint2 p = tmp[i];
        int pos = atomicAdd(&cur[(int)p.y - base_node], 1);
        idx_out[e0 + pos] = (int)p.x;
    }
}

// ================= encoder (MFMA bf16x6 ~ fp32-exact) =================

__global__ __launch_bounds__(256) void k_enc(const float* __restrict__ x,
                                             const unsigned* __restrict__ g_hm,
                                             const unsigned short* __restrict__ g_l,
                                             const float* __restrict__ bias,
                                             float* __restrict__ out, int ntiles) {
    __shared__ unsigned Whm[65 * 64];
    __shared__ unsigned short Wl[65 * 64];
    __shared__ float bs[64];
    stageP(g_hm, g_l, Whm, Wl);
    if (threadIdx.x < 64) bs[threadIdx.x] = bias[threadIdx.x];
    __syncthreads();
    int wave = threadIdx.x >> 6, lane = threadIdx.x & 63;
    int tile = blockIdx.x * 4 + wave;
    if (tile >= ntiles) return;
    int base = tile * 16;
    int m = lane & 15, quad = lane >> 4;
    short8 a1[2], a2[2], a3[2];
    afrag6(x + (size_t)base * 64, m, quad, 0, 64, a1[0], a2[0], a3[0]);
    afrag6(x + (size_t)base * 64, m, quad, 1, 64, a1[1], a2[1], a3[1]);
#pragma unroll
    for (int t = 0; t < 4; ++t) {
        f32x4 acc = gemm_tile6(Whm, Wl, t, lane, a1, a2, a3, bs[t * 16 + m]);
#pragma unroll
        for (int r = 0; r < 4; ++r)
            out[(size_t)(base + quad * 4 + r) * 64 + t * 16 + m] = acc[r];
    }
}

// ================= per-iteration pre (MFMA bf16x6): lx, v'; fp32-exact a,b =================

__global__ __launch_bounds__(256) void k_pre_iter(
    const float* __restrict__ x, const float* __restrict__ v_in, int first,
    const unsigned* __restrict__ vel_hm, const unsigned short* __restrict__ vel_l,
    const float* __restrict__ vel_b,
    const unsigned* __restrict__ lin_hm, const unsigned short* __restrict__ lin_l,
    const float* __restrict__ lin_b,
    const unsigned* __restrict__ diss_hm, const unsigned short* __restrict__ diss_l,
    const float* __restrict__ diss_b,
    const unsigned* __restrict__ forc_hm, const unsigned short* __restrict__ forc_l,
    const float* __restrict__ forc_b,
    const float* __restrict__ res_w,
    float* __restrict__ vp, float* __restrict__ lx,
    float* __restrict__ a, float* __restrict__ b, int ntiles) {
    __shared__ unsigned WAhm[65 * 64], WBhm[65 * 64];
    __shared__ unsigned short WAl[65 * 64], WBl[65 * 64];
    __shared__ float rsf[128];
    __shared__ float bl[64], bd[64], bfc[64], bv[64];
    stageP(lin_hm, lin_l, WAhm, WAl);
    stageP(diss_hm, diss_l, WBhm, WBl);
    if (threadIdx.x < 64) {
        bl[threadIdx.x]  = lin_b[threadIdx.x];
        bd[threadIdx.x]  = diss_b[threadIdx.x];
        bfc[threadIdx.x] = forc_b[threadIdx.x];
        bv[threadIdx.x]  = vel_b[threadIdx.x];
    }
    if (threadIdx.x < 128) rsf[threadIdx.x] = res_w[threadIdx.x];
    __syncthreads();
    int wave = threadIdx.x >> 6, lane = threadIdx.x & 63;
    int tile = blockIdx.x * 4 + wave;
    bool act = (tile < ntiles);
    int base = tile * 16;
    int m = lane & 15, quad = lane >> 4;
    short8 a1[2], a2[2], a3[2];
    f32x4 dacc[4];
    if (act) {
        float xr[16];
        const float* p = x + (size_t)base * 64 + m * 64;
#pragma unroll
        for (int hh = 0; hh < 2; ++hh)
#pragma unroll
            for (int j = 0; j < 8; ++j)
                xr[hh * 8 + j] = p[hh * 32 + quad * 8 + j];
#pragma unroll
        for (int hh = 0; hh < 2; ++hh)
#pragma unroll
            for (int j = 0; j < 8; ++j) {
                short s1, s2, s3;
                split3(xr[hh * 8 + j], s1, s2, s3);
                a1[hh][j] = s1; a2[hh][j] = s2; a3[hh][j] = s3;
            }
        // exact fp32 a = x@wa, b = x@wb (feeds relu->deg->rsqrt)
        float pa = 0.f, pb = 0.f;
#pragma unroll
        for (int hh = 0; hh < 2; ++hh)
#pragma unroll
            for (int j = 0; j < 8; ++j) {
                int k = hh * 32 + quad * 8 + j;
                float xv = xr[hh * 8 + j];
                pa = fmaf(xv, rsf[k], pa);
                pb = fmaf(xv, rsf[64 + k], pb);
            }
        pa += __shfl_xor(pa, 16, 64);
        pa += __shfl_xor(pa, 32, 64);
        pb += __shfl_xor(pb, 16, 64);
        pb += __shfl_xor(pb, 32, 64);
        if (quad == 0) { a[base + m] = pa; b[base + m] = pb; }
        // lin -> lx
#pragma unroll
        for (int t = 0; t < 4; ++t) {
            f32x4 acc = gemm_tile6(WAhm, WAl, t, lane, a1, a2, a3, bl[t * 16 + m]);
#pragma unroll
            for (int r = 0; r < 4; ++r)
                lx[(size_t)(base + quad * 4 + r) * 64 + t * 16 + m] = acc[r];
        }
        // diss (keep in regs)
#pragma unroll
        for (int t = 0; t < 4; ++t)
            dacc[t] = gemm_tile6(WBhm, WBl, t, lane, a1, a2, a3, bd[t * 16 + m]);
    }
    __syncthreads();
    stageP(forc_hm, forc_l, WAhm, WAl);
    if (first) stageP(vel_hm, vel_l, WBhm, WBl);
    __syncthreads();
    if (!act) return;
#pragma unroll
    for (int t = 0; t < 4; ++t) {
        f32x4 facc = gemm_tile6(WAhm, WAl, t, lane, a1, a2, a3, bfc[t * 16 + m]);
        f32x4 vv;
        if (first) {
            vv = gemm_tile6(WBhm, WBl, t, lane, a1, a2, a3, bv[t * 16 + m]);
        } else {
#pragma unroll
            for (int r = 0; r < 4; ++r)
                vv[r] = v_in[(size_t)(base + quad * 4 + r) * 64 + t * 16 + m];
        }
#pragma unroll
        for (int r = 0; r < 4; ++r) {
            float diss = fmaxf(dacc[t][r], 0.f);
            float vpv = vv[r] - EPSL * (diss * vv[r] - facc[r]);
            vp[(size_t)(base + quad * 4 + r) * 64 + t * 16 + m] = vpv;
        }
    }
}

// ================= per-iteration: deg, dinv, fp16 lxs (2-slice layout) =================
// slice s (s=0,1) holds features [s*32, s*32+32) node-major: lxs[s*NN*32 + node*32 + f]

__global__ __launch_bounds__(256) void k_deg_scale(
    const int* __restrict__ dsts_row, const int* __restrict__ starts_row,
    const float* __restrict__ a, const float* __restrict__ b,
    const float* __restrict__ rb_ptr,
    const float* __restrict__ lx,
    float* __restrict__ dinv,
    half_t* __restrict__ lxs, int n) {
    int wave = threadIdx.x >> 6, lane = threadIdx.x & 63;
    int node = blockIdx.x * 4 + wave;
    if (node >= n) return;
    float rb = rb_ptr[0];
    float a_s = a[node];
    int q0 = starts_row[node], q1 = starts_row[node + 1];
    float degsum = 0.f;
    for (int base = q0; base < q1; base += 64) {
        int idx = base + lane;
        if (idx < q1) {
            int d = dsts_row[idx];
            if (d != node) degsum += fmaxf(a_s + b[d] + rb, 0.f);
        }
    }
#pragma unroll
    for (int off = 32; off > 0; off >>= 1)
        degsum += __shfl_xor(degsum, off, 64);
    float di = (degsum > 0.f) ? (1.f / sqrtf(degsum)) : 0.f;
    if (lane == 0) dinv[node] = di;
    // feature = lane; slice = lane>>5, in-slice feature = lane&31
    lxs[(size_t)(lane >> 5) * NN * 32 + (size_t)node * 32 + (lane & 31)] =
        (half_t)(di * lx[node * 64 + lane]);
}

// ================= aggregation + state update (2 slice-phases, bit-identical math) =================

__global__ __launch_bounds__(256) void k_agg(
    const float* __restrict__ lx, const half_t* __restrict__ lxs,
    const int* __restrict__ srcs, const int* __restrict__ starts,
    const float* __restrict__ dinv,
    const float* __restrict__ a_in, const float* __restrict__ b_in,
    const float* __restrict__ rb_ptr,
    const float* __restrict__ vp,
    float* __restrict__ x, float* __restrict__ v, int n) {
    __shared__ float xch[4][64];
    int wave = threadIdx.x >> 6, lane = threadIdx.x & 63;
    int node = blockIdx.x * 4 + wave;
    bool valid = (node < n);
    float acc[8] = {0.f, 0.f, 0.f, 0.f, 0.f, 0.f, 0.f, 0.f};
    if (valid) {
        float rb = rb_ptr[0];
        float b_c = b_in[node];
        int g = lane >> 3, q = lane & 7;
        int p0 = starts[node], p1 = starts[node + 1];
        // two slice-phases: phase s covers features s*32 + q*4 .. +4 (uint2 = 4 fp16)
        for (int s = 0; s < 2; ++s) {
            const half_t* lxq = lxs + (size_t)s * NN * 32 + q * 4;
            float* accp = acc + s * 4;
            for (int base = p0; base < p1; base += 64) {
                int cnt = p1 - base; if (cnt > 64) cnt = 64;
                int sv = node;
                float rown = 0.f;
                if (lane < cnt) {
                    sv = srcs[base + lane];
                    if (sv != node) rown = fmaxf(a_in[sv] + b_c + rb, 0.f);
                }
                int srcv[8]; float w[8]; uint2 uu[8];
#pragma unroll
                for (int jj = 0; jj < 8; ++jj) {
                    srcv[jj] = __shfl(sv, jj * 8 + g, 64);
                    w[jj]    = __shfl(rown, jj * 8 + g, 64);
                }
#pragma unroll
                for (int jj = 0; jj < 8; ++jj)
                    uu[jj] = *(const uint2*)(lxq + (size_t)srcv[jj] * 32);
#pragma unroll
                for (int jj = 0; jj < 8; ++jj) {
                    union { uint2 u; half_t hh[4]; } U;
                    U.u = uu[jj];
#pragma unroll
                    for (int k = 0; k < 4; ++k)
                        accp[k] = fmaf(w[jj], (float)U.hh[k], accp[k]);
                }
            }
        }
#pragma unroll
        for (int k = 0; k < 8; ++k) {
            acc[k] += __shfl_xor(acc[k], 8, 64);
            acc[k] += __shfl_xor(acc[k], 16, 64);
            acc[k] += __shfl_xor(acc[k], 32, 64);
        }
        if (lane < 8) {
            // phase 0: features lane*4+k ; phase 1: features 32+lane*4+k
#pragma unroll
            for (int k = 0; k < 4; ++k) xch[wave][lane * 4 + k] = acc[k];
#pragma unroll
            for (int k = 0; k < 4; ++k) xch[wave][32 + lane * 4 + k] = acc[4 + k];
        }
    }
    __syncthreads();
    if (!valid) return;
    float agg = xch[wave][lane];
    size_t off = (size_t)node * 64 + lane;
    float conv = lx[off] - dinv[node] * agg;
    float vn = vp[off] - EPSL * conv;
    float xn = x[off] + EPSL * vn;
    v[off] = vn;
    x[off] = xn;
}

// ================= MLP residual (MFMA bf16x6) =================

__global__ __launch_bounds__(256) void k_mlp(
    float* __restrict__ h,
    const unsigned* __restrict__ w1_hm, const unsigned short* __restrict__ w1_l,
    const float* __restrict__ b1,
    const unsigned* __restrict__ w2_hm, const unsigned short* __restrict__ w2_l,
    const float* __restrict__ b2, int ntiles) {
    __shared__ unsigned W1hm[65 * 64], W2hm[65 * 64];
    __shared__ unsigned short W1l[65 * 64], W2l[65 * 64];
    __shared__ float B1[64], B2[64];
    __shared__ float G[4][16 * 68];
    stageP(w1_hm, w1_l, W1hm, W1l);
    stageP(w2_hm, w2_l, W2hm, W2l);
    if (threadIdx.x < 64) { B1[threadIdx.x] = b1[threadIdx.x]; B2[threadIdx.x] = b2[threadIdx.x]; }
    __syncthreads();
    int wave = threadIdx.x >> 6, lane = threadIdx.x & 63;
    int tile = blockIdx.x * 4 + wave;
    bool act = (tile < ntiles);
    int base = tile * 16;
    int m = lane & 15, quad = lane >> 4;
    short8 a1[2], a2[2], a3[2];
    float* g = G[wave];
    if (act) {
        afrag6(h + (size_t)base * 64, m, quad, 0, 64, a1[0], a2[0], a3[0]);
        afrag6(h + (size_t)base * 64, m, quad, 1, 64, a1[1], a2[1], a3[1]);
#pragma unroll
        for (int t = 0; t < 4; ++t) {
            f32x4 acc = gemm_tile6(W1hm, W1l, t, lane, a1, a2, a3, B1[t * 16 + m]);
#pragma unroll
            for (int r = 0; r < 4; ++r) {
                float tt = acc[r];
                float z = 0.7978845608028654f * (tt + 0.044715f * tt * tt * tt);
                g[(quad * 4 + r) * 68 + t * 16 + m] = 0.5f * tt * (1.f + tanhf(z));
            }
        }
    }
    __syncthreads();
    if (!act) return;
    short8 g1[2], g2[2], g3[2];
    afrag6(g, m, quad, 0, 68, g1[0], g2[0], g3[0]);
    afrag6(g, m, quad, 1, 68, g1[1], g2[1], g3[1]);
#pragma unroll
    for (int t = 0; t < 4; ++t) {
        f32x4 acc = gemm_tile6(W2hm, W2l, t, lane, g1, g2, g3, B2[t * 16 + m]);
#pragma unroll
        for (int r = 0; r < 4; ++r) {
            size_t off = (size_t)(base + quad * 4 + r) * 64 + t * 16 + m;
            h[off] = h[off] + acc[r];
        }
    }
}

// ================= final MLP + decoder fused (MLP bf16x6, dec bf16x3 terminal) =================

__global__ __launch_bounds__(256) void k_mlp_dec(
    const float* __restrict__ h,
    const unsigned* __restrict__ w1_hm, const unsigned short* __restrict__ w1_l,
    const float* __restrict__ b1,
    const unsigned* __restrict__ w2_hm, const unsigned short* __restrict__ w2_l,
    const float* __restrict__ b2,
    const unsigned* __restrict__ dec_hm, const float* __restrict__ dec_b,
    float* __restrict__ out, int ntiles) {
    __shared__ unsigned W1hm[65 * 64], W2hm[65 * 64], Wdp[33 * 64];
    __shared__ unsigned short W1l[65 * 64], W2l[65 * 64];
    __shared__ float B1[64], B2[64], Bd[32];
    __shared__ float G[4][16 * 68];
    stageP(w1_hm, w1_l, W1hm, W1l);
    stageP(w2_hm, w2_l, W2hm, W2l);
    for (int i = threadIdx.x; i < 2048; i += 256) {
        int k = i >> 5, n = i & 31;
        Wdp[k * 33 + n] = dec_hm[i];
    }
    if (threadIdx.x < 64) { B1[threadIdx.x] = b1[threadIdx.x]; B2[threadIdx.x] = b2[threadIdx.x]; }
    if (threadIdx.x < 32) Bd[threadIdx.x] = dec_b[threadIdx.x];
    __syncthreads();
    int wave = threadIdx.x >> 6, lane = threadIdx.x & 63;
    int tile = blockIdx.x * 4 + wave;
    bool act = (tile < ntiles);
    int base = tile * 16;
    int m = lane & 15, quad = lane >> 4;
    short8 a1[2], a2[2], a3[2];
    float* g = G[wave];
    if (act) {
        afrag6(h + (size_t)base * 64, m, quad, 0, 64, a1[0], a2[0], a3[0]);
        afrag6(h + (size_t)base * 64, m, quad, 1, 64, a1[1], a2[1], a3[1]);
#pragma unroll
        for (int t = 0; t < 4; ++t) {
            f32x4 acc = gemm_tile6(W1hm, W1l, t, lane, a1, a2, a3, B1[t * 16 + m]);
#pragma unroll
            for (int r = 0; r < 4; ++r) {
                float tt = acc[r];
                float z = 0.7978845608028654f * (tt + 0.044715f * tt * tt * tt);
                g[(quad * 4 + r) * 68 + t * 16 + m] = 0.5f * tt * (1.f + tanhf(z));
            }
        }
    }
    __syncthreads();
    short8 g1[2], g2[2], g3[2];
    if (act) {
        afrag6(g, m, quad, 0, 68, g1[0], g2[0], g3[0]);
        afrag6(g, m, quad, 1, 68, g1[1], g2[1], g3[1]);
    }
    __syncthreads();   // G about to be overwritten with hn
    if (act) {
#pragma unroll
        for (int t = 0; t < 4; ++t) {
            f32x4 acc = gemm_tile6(W2hm, W2l, t, lane, g1, g2, g3, B2[t * 16 + m]);
#pragma unroll
            for (int r = 0; r < 4; ++r) {
                size_t off = (size_t)(base + quad * 4 + r) * 64 + t * 16 + m;
                g[(quad * 4 + r) * 68 + t * 16 + m] = h[off] + acc[r];
            }
        }
    }
    __syncthreads();
    if (!act) return;
    short8 h1[2], h2[2], h3[2];
    afrag6(g, m, quad, 0, 68, h1[0], h2[0], h3[0]);
    afrag6(g, m, quad, 1, 68, h1[1], h2[1], h3[1]);
#pragma unroll
    for (int t = 0; t < 2; ++t) {
        int n = t * 16 + m;
        f32x4 acc = {Bd[n], Bd[n], Bd[n], Bd[n]};
#pragma unroll
        for (int hh = 0; hh < 2; ++hh) {
            short8 bh, bm;
            int k0 = hh * 32 + quad * 8;
#pragma unroll
            for (int j = 0; j < 8; ++j) {
                unsigned u = Wdp[(k0 + j) * 33 + n];
                bh[j] = (short)(u >> 16);
                bm[j] = (short)(u & 0xffffu);
            }
            acc = MFMAB(h1[hh], bh, acc);
            acc = MFMAB(h1[hh], bm, acc);
            acc = MFMAB(h2[hh], bh, acc);
        }
#pragma unroll
        for (int r = 0; r < 4; ++r)
            out[(size_t)(base + quad * 4 + r) * 32 + n] = acc[r];
    }
}

// ================= launch =================

extern "C" void kernel_launch(void* const* d_in, const int* in_sizes, int n_in,
                              void* d_out, int out_size, void* d_ws, size_t ws_size,
                              hipStream_t stream) {
    const float* x_in   = (const float*)d_in[0];
    const int*   eidx   = (const int*)d_in[1];
    const float* enc_w  = (const float*)d_in[2];
    const float* enc_b  = (const float*)d_in[3];
    const float* vel_w  = (const float*)d_in[4];
    const float* vel_b  = (const float*)d_in[5];
    const float* res_w  = (const float*)d_in[6];
    const float* res_b  = (const float*)d_in[7];
    const float* lin_w  = (const float*)d_in[8];
    const float* lin_b  = (const float*)d_in[9];
    const float* diss_w = (const float*)d_in[10];
    const float* diss_b = (const float*)d_in[11];
    const float* forc_w = (const float*)d_in[12];
    const float* forc_b = (const float*)d_in[13];
    const float* mlp_w1 = (const float*)d_in[14];
    const float* mlp_b1 = (const float*)d_in[15];
    const float* mlp_w2 = (const float*)d_in[16];
    const float* mlp_b2 = (const float*)d_in[17];
    const float* dec_w  = (const float*)d_in[18];
    const float* dec_b  = (const float*)d_in[19];
    float* out = (float*)d_out;

    const int Nn = NN, Ee = EE;
    const int* row = eidx;
    const int* col = eidx + Ee;

    char* wsp = (char*)d_ws;
    auto alloc = [&](size_t bytes) {
        char* p = wsp;
        wsp += ((bytes + 255) & ~(size_t)255);
        return p;
    };
    float*  h          = (float*)alloc((size_t)Nn * 64 * 4);
    float*  v          = (float*)alloc((size_t)Nn * 64 * 4);
    float*  lx         = (float*)alloc((size_t)Nn * 64 * 4);
    float*  vp         = (float*)alloc((size_t)Ee * 8);     // aliases CSR tmp (25.6 MB each)
    half_t* lxs        = (half_t*)alloc((size_t)2 * NN * 32 * 2);   // 2 feature-slices
    float*  aA         = (float*)alloc((size_t)Nn * 4);
    float*  bA         = (float*)alloc((size_t)Nn * 4);
    float*  dinv       = (float*)alloc((size_t)Nn * 4);
    int*    srcs_col   = (int*)alloc((size_t)Ee * 4);
    int*    dsts_row   = (int*)alloc((size_t)Ee * 4);
    int*    starts_col = (int*)alloc((size_t)(Nn + 1) * 4);
    int*    starts_row = (int*)alloc((size_t)(Nn + 1) * 4);
    int*    bc         = (int*)alloc((size_t)2 * KB * 4);
    int*    bs_col     = (int*)alloc((size_t)(KB + 1) * 4);
    int*    bs_row     = (int*)alloc((size_t)(KB + 1) * 4);
    int*    cur_col    = (int*)alloc((size_t)KB * 4);
    int*    cur_row    = (int*)alloc((size_t)KB * 4);
    unsigned*       Whm_all = (unsigned*)alloc((size_t)(DEC_OFF + 2048) * 4);
    unsigned short* Wl_all  = (unsigned short*)alloc((size_t)(DEC_OFF + 2048) * 2);
    uint2* tmp = (uint2*)vp;   // CSR build finishes before vp is first written
    int* bc_col = bc;
    int* bc_row = bc + KB;

    const int TPB = 256;
    const int gridN4 = (Nn + 3) / 4;
    const int gridS  = (Ee + 2047) / 2048;

    // ---- weight pre-split (once per launch) ----
    k_prep<<<14, TPB, 0, stream>>>(enc_w, lin_w, diss_w, forc_w, vel_w,
                                   mlp_w1, mlp_w2, dec_w, Whm_all, Wl_all);

    // ---- CSR build ----
    hipMemsetAsync(bc, 0, (size_t)2 * KB * 4, stream);
    k_hist2<<<1024, TPB, 0, stream>>>(row, col, bc_row, bc_col, Ee);
    k_scan_buckets<<<1, 512, 0, stream>>>(bc_col, bc_row, bs_col, bs_row, cur_col, cur_row);
    k_bucket_scatter<<<gridS, TPB, 0, stream>>>(col, row, cur_col, tmp, Ee);
    k_bucket_finalize<<<KB, TPB, 0, stream>>>(tmp, bs_col, starts_col, srcs_col, Nn);
    k_bucket_scatter<<<gridS, TPB, 0, stream>>>(row, col, cur_row, tmp, Ee);
    k_bucket_finalize<<<KB, TPB, 0, stream>>>(tmp, bs_row, starts_row, dsts_row, Nn);

    // ---- encoder ----
    k_enc<<<GRIDT, TPB, 0, stream>>>(x_in, Whm_all, Wl_all, enc_b, h, NTILES);

    for (int j = 0; j < 2; ++j) {
        const float* vb  = vel_b  + j * 64;
        const float* rw  = res_w  + j * 128;
        const float* rbp = res_b  + j;
        const float* lb  = lin_b  + j * 64;
        const float* db  = diss_b + j * 64;
        const float* fb  = forc_b + j * 64;
        const unsigned* lin_hm  = Whm_all + (size_t)(1 + j) * 4096;
        const unsigned short* lin_l = Wl_all + (size_t)(1 + j) * 4096;
        const unsigned* diss_hm = Whm_all + (size_t)(3 + j) * 4096;
        const unsigned short* diss_l = Wl_all + (size_t)(3 + j) * 4096;
        const unsigned* forc_hm = Whm_all + (size_t)(5 + j) * 4096;
        const unsigned short* forc_l = Wl_all + (size_t)(5 + j) * 4096;
        const unsigned* vel_hm  = Whm_all + (size_t)(7 + j) * 4096;
        const unsigned short* vel_l = Wl_all + (size_t)(7 + j) * 4096;

        for (int it = 0; it < 4; ++it) {
            k_pre_iter<<<GRIDT, TPB, 0, stream>>>(h, v, (it == 0) ? 1 : 0,
                                                  vel_hm, vel_l, vb,
                                                  lin_hm, lin_l, lb,
                                                  diss_hm, diss_l, db,
                                                  forc_hm, forc_l, fb,
                                                  rw, vp, lx, aA, bA, NTILES);
            k_deg_scale<<<gridN4, TPB, 0, stream>>>(dsts_row, starts_row, aA, bA, rbp,
                                                    lx, dinv, lxs, Nn);
            k_agg<<<gridN4, TPB, 0, stream>>>(lx, lxs, srcs_col, starts_col, dinv,
                                              aA, bA, rbp, vp, h, v, Nn);
        }

        if (j == 0)
            k_mlp<<<GRIDT, TPB, 0, stream>>>(h,
                                             Whm_all + (size_t)9 * 4096, Wl_all + (size_t)9 * 4096,
                                             mlp_b1,
                                             Whm_all + (size_t)11 * 4096, Wl_all + (size_t)11 * 4096,
                                             mlp_b2, NTILES);
        else
            k_mlp_dec<<<GRIDT, TPB, 0, stream>>>(h,
                                                 Whm_all + (size_t)10 * 4096, Wl_all + (size_t)10 * 4096,
                                                 mlp_b1 + 64,
                                                 Whm_all + (size_t)12 * 4096, Wl_all + (size_t)12 * 4096,
                                                 mlp_b2 + 64,
                                                 Whm_all + DEC_OFF, dec_b, out, NTILES);
    }
}

// Round 12
// 1743.641 us; speedup vs baseline: 1.0639x; 1.0639x over previous
//
#include <hip/hip_runtime.h>
#include <math.h>

#define NN 100000
#define EE 3200000
#define EPSL 0.01f
#define KB 391
#define NTILES 6250          // NN/16 exactly
#define GRIDT 1563           // ceil(6250/4)
#define DEC_OFF (13 * 4096)  // plane-buffer offset of decoder weights

typedef _Float16 half_t;
typedef __attribute__((ext_vector_type(8))) short short8;
typedef __attribute__((ext_vector_type(4))) float f32x4;

#define MFMAB(a, b, c) __builtin_amdgcn_mfma_f32_16x16x32_bf16(a, b, c, 0, 0, 0)

__device__ __forceinline__ short f2bfh(float f) {
    union { float f; unsigned u; } c; c.f = f;
    unsigned u = c.u + (0x7fffu + ((c.u >> 16) & 1u));
    return (short)(u >> 16);
}
__device__ __forceinline__ float bfh2f(short s) {
    union { unsigned u; float f; } c;
    c.u = ((unsigned)(unsigned short)s) << 16;
    return c.f;
}
// fp32 -> 3-term bf16 split (a = s1+s2+s3 with ~2^-24 residual)
__device__ __forceinline__ void split3(float f, short& s1, short& s2, short& s3) {
    s1 = f2bfh(f);
    float r = f - bfh2f(s1);
    s2 = f2bfh(r);
    r = r - bfh2f(s2);
    s3 = f2bfh(r);
}

// A-frags (3 planes) from row-major fp32: lane m=lane&15, quad=lane>>4
__device__ __forceinline__ void afrag6(const float* __restrict__ xb, int m, int quad,
                                       int hh, int stride, short8& a1, short8& a2, short8& a3) {
    const float* p = xb + m * stride + hh * 32 + quad * 8;
#pragma unroll
    for (int j = 0; j < 8; ++j) {
        short s1, s2, s3;
        split3(p[j], s1, s2, s3);
        a1[j] = s1; a2[j] = s2; a3[j] = s3;
    }
}

// B-frags from staged LDS: Whm = (s1<<16|s2) u32 stride 65, Wl = s3 u16 stride 65
__device__ __forceinline__ f32x4 gemm_tile6(const unsigned* Whm, const unsigned short* Wl,
                                            int t, int lane,
                                            const short8* a1, const short8* a2, const short8* a3,
                                            float bias) {
    f32x4 acc = {bias, bias, bias, bias};
    int n = t * 16 + (lane & 15);
    int q8 = (lane >> 4) * 8;
#pragma unroll
    for (int hh = 0; hh < 2; ++hh) {
        short8 bh, bm, bl;
        int k0 = hh * 32 + q8;
#pragma unroll
        for (int j = 0; j < 8; ++j) {
            unsigned u = Whm[(k0 + j) * 65 + n];
            bh[j] = (short)(u >> 16);
            bm[j] = (short)(u & 0xffffu);
            bl[j] = (short)Wl[(k0 + j) * 65 + n];
        }
        acc = MFMAB(a1[hh], bh, acc);
        acc = MFMAB(a1[hh], bm, acc);
        acc = MFMAB(a2[hh], bh, acc);
        acc = MFMAB(a1[hh], bl, acc);
        acc = MFMAB(a2[hh], bm, acc);
        acc = MFMAB(a3[hh], bh, acc);
    }
    return acc;
}
// stage pre-split planes (global, compact [k*64+n]) into padded LDS (stride 65)
__device__ __forceinline__ void stageP(const unsigned* __restrict__ g_hm,
                                       const unsigned short* __restrict__ g_l,
                                       unsigned* Whm, unsigned short* Wl) {
    for (int i = threadIdx.x; i < 4096; i += 256) {
        int k = i >> 6, n = i & 63;
        Whm[k * 65 + n] = g_hm[i];
        Wl[k * 65 + n] = g_l[i];
    }
}

// ================= weight pre-split (once per launch) =================
// slots: 0 enc | 1,2 lin | 3,4 diss | 5,6 forc | 7,8 vel | 9,10 mlp_w1 | 11,12 mlp_w2 | 13 dec(2048)

__global__ __launch_bounds__(256) void k_prep(const float* __restrict__ enc_w,
                                              const float* __restrict__ lin_w,
                                              const float* __restrict__ diss_w,
                                              const float* __restrict__ forc_w,
                                              const float* __restrict__ vel_w,
                                              const float* __restrict__ w1,
                                              const float* __restrict__ w2,
                                              const float* __restrict__ dec_w,
                                              unsigned* __restrict__ Whm,
                                              unsigned short* __restrict__ Wl) {
    int slot = blockIdx.x;
    const float* src;
    int size = 4096;
    int off = slot * 4096;
    switch (slot) {
        case 0:  src = enc_w; break;
        case 1:  case 2:  src = lin_w  + (slot - 1)  * 4096; break;
        case 3:  case 4:  src = diss_w + (slot - 3)  * 4096; break;
        case 5:  case 6:  src = forc_w + (slot - 5)  * 4096; break;
        case 7:  case 8:  src = vel_w  + (slot - 7)  * 4096; break;
        case 9:  case 10: src = w1     + (slot - 9)  * 4096; break;
        case 11: case 12: src = w2     + (slot - 11) * 4096; break;
        default: src = dec_w; size = 2048; break;
    }
    for (int i = threadIdx.x; i < size; i += 256) {
        short s1, s2, s3;
        split3(src[i], s1, s2, s3);
        Whm[off + i] = (((unsigned)(unsigned short)s1) << 16) | (unsigned)(unsigned short)s2;
        Wl[off + i] = (unsigned short)s3;
    }
}

// ================= CSR build (unchanged) =================

__global__ __launch_bounds__(256) void k_hist2(const int* __restrict__ row,
                                               const int* __restrict__ col,
                                               int* __restrict__ bc_row,
                                               int* __restrict__ bc_col, int e) {
    __shared__ int hr[KB], hc[KB];
    for (int i = threadIdx.x; i < KB; i += 256) { hr[i] = 0; hc[i] = 0; }
    __syncthreads();
    for (int i = blockIdx.x * 256 + threadIdx.x; i < e; i += gridDim.x * 256) {
        atomicAdd(&hr[row[i] >> 8], 1);
        atomicAdd(&hc[col[i] >> 8], 1);
    }
    __syncthreads();
    for (int i = threadIdx.x; i < KB; i += 256) {
        if (hr[i]) atomicAdd(&bc_row[i], hr[i]);
        if (hc[i]) atomicAdd(&bc_col[i], hc[i]);
    }
}

__global__ __launch_bounds__(512) void k_scan_buckets(const int* __restrict__ bc_col,
                                                      const int* __restrict__ bc_row,
                                                      int* __restrict__ bs_col,
                                                      int* __restrict__ bs_row,
                                                      int* __restrict__ cur_col,
                                                      int* __restrict__ cur_row) {
    __shared__ int s[512];
    int i = threadIdx.x;
    int v = (i < KB) ? bc_col[i] : 0;
    s[i] = v; __syncthreads();
    for (int off = 1; off < 512; off <<= 1) {
        int t = (i >= off) ? s[i - off] : 0;
        __syncthreads(); s[i] += t; __syncthreads();
    }
    if (i < KB) { int ex = s[i] - v; bs_col[i] = ex; cur_col[i] = ex; }
    if (i == 511) bs_col[KB] = s[511];
    __syncthreads();
    v = (i < KB) ? bc_row[i] : 0;
    s[i] = v; __syncthreads();
    for (int off = 1; off < 512; off <<= 1) {
        int t = (i >= off) ? s[i - off] : 0;
        __syncthreads(); s[i] += t; __syncthreads();
    }
    if (i < KB) { int ex = s[i] - v; bs_row[i] = ex; cur_row[i] = ex; }
    if (i == 511) bs_row[KB] = s[511];
}

__global__ __launch_bounds__(256) void k_bucket_scatter(const int* __restrict__ keys,
                                                        const int* __restrict__ vals,
                                                        int* __restrict__ cursors,
                                                        uint2* __restrict__ tmp, int e) {
    __shared__ int lcnt[KB];
    __shared__ int lbase[KB];
    for (int i = threadIdx.x; i < KB; i += 256) lcnt[i] = 0;
    __syncthreads();
    int tile = blockIdx.x * 2048;
    int kv[8], vv[8], rk[8];
#pragma unroll
    for (int u = 0; u < 8; ++u) {
        int i = tile + u * 256 + threadIdx.x;
        if (i < e) {
            kv[u] = keys[i];
            vv[u] = vals[i];
            rk[u] = atomicAdd(&lcnt[kv[u] >> 8], 1);
        } else kv[u] = -1;
    }
    __syncthreads();
    for (int i = threadIdx.x; i < KB; i += 256) {
        int c = lcnt[i];
        if (c) lbase[i] = atomicAdd(&cursors[i], c);
    }
    __syncthreads();
#pragma unroll
    for (int u = 0; u < 8; ++u) {
        if (kv[u] >= 0)
            tmp[lbase[kv[u] >> 8] + rk[u]] = make_uint2((unsigned)vv[u], (unsigned)kv[u]);
    }
}

__global__ __launch_bounds__(256) void k_bucket_finalize(const uint2* __restrict__ tmp,
                                                         const int* __restrict__ bstarts,
                                                         int* __restrict__ starts_out,
                                                         int* __restrict__ idx_out, int n) {
    __shared__ int hist[256], cur[256], ss[256];
    int b = blockIdx.x;
    int base_node = b << 8;
    int e0 = bstarts[b], e1 = bstarts[b + 1];
    hist[threadIdx.x] = 0;
    __syncthreads();
    for (int i = e0 + (int)threadIdx.x; i < e1; i += 256)
        atomicAdd(&hist[(int)tmp[i].y - base_node], 1);
    __syncthreads();
    int v = hist[threadIdx.x];
    ss[threadIdx.x] = v; __syncthreads();
    for (int off = 1; off < 256; off <<= 1) {
        int t = (threadIdx.x >= (unsigned)off) ? ss[threadIdx.x - off] : 0;
        __syncthreads(); ss[threadIdx.x] += t; __syncthreads();
    }
    int excl = ss[threadIdx.x] - v;
    int node = base_node + (int)threadIdx.x;
    if (node < n) starts_out[node] = e0 + excl;
    if (b == (int)gridDim.x - 1 && threadIdx.x == 0) starts_out[n] = e1;
    cur[threadIdx.x] = excl;
    __syncthreads();
    for (int i = e0 + (int)threadIdx.x; i < e1; i += 256) {
        uint2 p = tmp[i];
        int pos = atomicAdd(&cur[(int)p.y - base_node], 1);
        idx_out[e0 + pos] = (int)p.x;
    }
}

// ================= encoder (MFMA bf16x6 ~ fp32-exact) =================

__global__ __launch_bounds__(256) void k_enc(const float* __restrict__ x,
                                             const unsigned* __restrict__ g_hm,
                                             const unsigned short* __restrict__ g_l,
                                             const float* __restrict__ bias,
                                             float* __restrict__ out, int ntiles) {
    __shared__ unsigned Whm[65 * 64];
    __shared__ unsigned short Wl[65 * 64];
    __shared__ float bs[64];
    stageP(g_hm, g_l, Whm, Wl);
    if (threadIdx.x < 64) bs[threadIdx.x] = bias[threadIdx.x];
    __syncthreads();
    int wave = threadIdx.x >> 6, lane = threadIdx.x & 63;
    int tile = blockIdx.x * 4 + wave;
    if (tile >= ntiles) return;
    int base = tile * 16;
    int m = lane & 15, quad = lane >> 4;
    short8 a1[2], a2[2], a3[2];
    afrag6(x + (size_t)base * 64, m, quad, 0, 64, a1[0], a2[0], a3[0]);
    afrag6(x + (size_t)base * 64, m, quad, 1, 64, a1[1], a2[1], a3[1]);
#pragma unroll
    for (int t = 0; t < 4; ++t) {
        f32x4 acc = gemm_tile6(Whm, Wl, t, lane, a1, a2, a3, bs[t * 16 + m]);
#pragma unroll
        for (int r = 0; r < 4; ++r)
            out[(size_t)(base + quad * 4 + r) * 64 + t * 16 + m] = acc[r];
    }
}

// ================= per-iteration pre (MFMA bf16x6): lx, v'; fp32-exact a,b =================

__global__ __launch_bounds__(256) void k_pre_iter(
    const float* __restrict__ x, const float* __restrict__ v_in, int first,
    const unsigned* __restrict__ vel_hm, const unsigned short* __restrict__ vel_l,
    const float* __restrict__ vel_b,
    const unsigned* __restrict__ lin_hm, const unsigned short* __restrict__ lin_l,
    const float* __restrict__ lin_b,
    const unsigned* __restrict__ diss_hm, const unsigned short* __restrict__ diss_l,
    const float* __restrict__ diss_b,
    const unsigned* __restrict__ forc_hm, const unsigned short* __restrict__ forc_l,
    const float* __restrict__ forc_b,
    const float* __restrict__ res_w,
    float* __restrict__ vp, float* __restrict__ lx,
    float* __restrict__ a, float* __restrict__ b, int ntiles) {
    __shared__ unsigned WAhm[65 * 64], WBhm[65 * 64];
    __shared__ unsigned short WAl[65 * 64], WBl[65 * 64];
    __shared__ float rsf[128];
    __shared__ float bl[64], bd[64], bfc[64], bv[64];
    stageP(lin_hm, lin_l, WAhm, WAl);
    stageP(diss_hm, diss_l, WBhm, WBl);
    if (threadIdx.x < 64) {
        bl[threadIdx.x]  = lin_b[threadIdx.x];
        bd[threadIdx.x]  = diss_b[threadIdx.x];
        bfc[threadIdx.x] = forc_b[threadIdx.x];
        bv[threadIdx.x]  = vel_b[threadIdx.x];
    }
    if (threadIdx.x < 128) rsf[threadIdx.x] = res_w[threadIdx.x];
    __syncthreads();
    int wave = threadIdx.x >> 6, lane = threadIdx.x & 63;
    int tile = blockIdx.x * 4 + wave;
    bool act = (tile < ntiles);
    int base = tile * 16;
    int m = lane & 15, quad = lane >> 4;
    short8 a1[2], a2[2], a3[2];
    f32x4 dacc[4];
    if (act) {
        float xr[16];
        const float* p = x + (size_t)base * 64 + m * 64;
#pragma unroll
        for (int hh = 0; hh < 2; ++hh)
#pragma unroll
            for (int j = 0; j < 8; ++j)
                xr[hh * 8 + j] = p[hh * 32 + quad * 8 + j];
#pragma unroll
        for (int hh = 0; hh < 2; ++hh)
#pragma unroll
            for (int j = 0; j < 8; ++j) {
                short s1, s2, s3;
                split3(xr[hh * 8 + j], s1, s2, s3);
                a1[hh][j] = s1; a2[hh][j] = s2; a3[hh][j] = s3;
            }
        // exact fp32 a = x@wa, b = x@wb (feeds relu->deg->rsqrt)
        float pa = 0.f, pb = 0.f;
#pragma unroll
        for (int hh = 0; hh < 2; ++hh)
#pragma unroll
            for (int j = 0; j < 8; ++j) {
                int k = hh * 32 + quad * 8 + j;
                float xv = xr[hh * 8 + j];
                pa = fmaf(xv, rsf[k], pa);
                pb = fmaf(xv, rsf[64 + k], pb);
            }
        pa += __shfl_xor(pa, 16, 64);
        pa += __shfl_xor(pa, 32, 64);
        pb += __shfl_xor(pb, 16, 64);
        pb += __shfl_xor(pb, 32, 64);
        if (quad == 0) { a[base + m] = pa; b[base + m] = pb; }
        // lin -> lx
#pragma unroll
        for (int t = 0; t < 4; ++t) {
            f32x4 acc = gemm_tile6(WAhm, WAl, t, lane, a1, a2, a3, bl[t * 16 + m]);
#pragma unroll
            for (int r = 0; r < 4; ++r)
                lx[(size_t)(base + quad * 4 + r) * 64 + t * 16 + m] = acc[r];
        }
        // diss (keep in regs)
#pragma unroll
        for (int t = 0; t < 4; ++t)
            dacc[t] = gemm_tile6(WBhm, WBl, t, lane, a1, a2, a3, bd[t * 16 + m]);
    }
    __syncthreads();
    stageP(forc_hm, forc_l, WAhm, WAl);
    if (first) stageP(vel_hm, vel_l, WBhm, WBl);
    __syncthreads();
    if (!act) return;
#pragma unroll
    for (int t = 0; t < 4; ++t) {
        f32x4 facc = gemm_tile6(WAhm, WAl, t, lane, a1, a2, a3, bfc[t * 16 + m]);
        f32x4 vv;
        if (first) {
            vv = gemm_tile6(WBhm, WBl, t, lane, a1, a2, a3, bv[t * 16 + m]);
        } else {
#pragma unroll
            for (int r = 0; r < 4; ++r)
                vv[r] = v_in[(size_t)(base + quad * 4 + r) * 64 + t * 16 + m];
        }
#pragma unroll
        for (int r = 0; r < 4; ++r) {
            float diss = fmaxf(dacc[t][r], 0.f);
            float vpv = vv[r] - EPSL * (diss * vv[r] - facc[r]);
            vp[(size_t)(base + quad * 4 + r) * 64 + t * 16 + m] = vpv;
        }
    }
}

// ================= per-iteration: deg, dinv, fp16 lxs (round-10 layout) =================

__global__ __launch_bounds__(256) void k_deg_scale(
    const int* __restrict__ dsts_row, const int* __restrict__ starts_row,
    const float* __restrict__ a, const float* __restrict__ b,
    const float* __restrict__ rb_ptr,
    const float* __restrict__ lx,
    float* __restrict__ dinv,
    half_t* __restrict__ lxs, int n) {
    int wave = threadIdx.x >> 6, lane = threadIdx.x & 63;
    int node = blockIdx.x * 4 + wave;
    if (node >= n) return;
    float rb = rb_ptr[0];
    float a_s = a[node];
    int q0 = starts_row[node], q1 = starts_row[node + 1];
    float degsum = 0.f;
    for (int base = q0; base < q1; base += 64) {
        int idx = base + lane;
        if (idx < q1) {
            int d = dsts_row[idx];
            if (d != node) degsum += fmaxf(a_s + b[d] + rb, 0.f);
        }
    }
#pragma unroll
    for (int off = 32; off > 0; off >>= 1)
        degsum += __shfl_xor(degsum, off, 64);
    float di = (degsum > 0.f) ? (1.f / sqrtf(degsum)) : 0.f;
    if (lane == 0) dinv[node] = di;
    lxs[node * 64 + lane] = (half_t)(di * lx[node * 64 + lane]);
}

// ================= aggregation + state update (uint4 gathers, degree-bounded loop) =================
// skipped slot-groups have w==0 exactly -> fmaf(0,finite,acc)==acc -> bit-identical.

__global__ __launch_bounds__(256) void k_agg(
    const float* __restrict__ lx, const half_t* __restrict__ lxs,
    const int* __restrict__ srcs, const int* __restrict__ starts,
    const float* __restrict__ dinv,
    const float* __restrict__ a_in, const float* __restrict__ b_in,
    const float* __restrict__ rb_ptr,
    const float* __restrict__ vp,
    float* __restrict__ x, float* __restrict__ v, int n) {
    __shared__ float xch[4][64];
    int wave = threadIdx.x >> 6, lane = threadIdx.x & 63;
    int node = blockIdx.x * 4 + wave;
    bool valid = (node < n);
    float acc[8] = {0.f, 0.f, 0.f, 0.f, 0.f, 0.f, 0.f, 0.f};
    if (valid) {
        float rb = rb_ptr[0];
        float b_c = b_in[node];
        int g = lane >> 3, q = lane & 7;
        int p0 = starts[node], p1 = starts[node + 1];
        const half_t* lxq = lxs + q * 8;
        for (int base = p0; base < p1; base += 64) {
            int cnt = p1 - base; if (cnt > 64) cnt = 64;
            int nj = (cnt + 7) >> 3;    // wave-uniform group count
            int sv = node;
            float rown = 0.f;
            if (lane < cnt) {
                sv = srcs[base + lane];
                if (sv != node) rown = fmaxf(a_in[sv] + b_c + rb, 0.f);
            }
            int srcv[8]; float w[8]; uint4 uu[8];
#pragma unroll
            for (int jj = 0; jj < 8; ++jj) {
                if (jj < nj) {
                    srcv[jj] = __shfl(sv, jj * 8 + g, 64);
                    w[jj]    = __shfl(rown, jj * 8 + g, 64);
                }
            }
#pragma unroll
            for (int jj = 0; jj < 8; ++jj)
                if (jj < nj) uu[jj] = *(const uint4*)(lxq + (size_t)srcv[jj] * 64);
#pragma unroll
            for (int jj = 0; jj < 8; ++jj) {
                if (jj < nj) {
                    union { uint4 u; half_t hh[8]; } U;
                    U.u = uu[jj];
#pragma unroll
                    for (int k = 0; k < 8; ++k)
                        acc[k] = fmaf(w[jj], (float)U.hh[k], acc[k]);
                }
            }
        }
#pragma unroll
        for (int k = 0; k < 8; ++k) {
            acc[k] += __shfl_xor(acc[k], 8, 64);
            acc[k] += __shfl_xor(acc[k], 16, 64);
            acc[k] += __shfl_xor(acc[k], 32, 64);
        }
        if (lane < 8) {
#pragma unroll
            for (int k = 0; k < 8; ++k) xch[wave][lane * 8 + k] = acc[k];
        }
    }
    __syncthreads();
    if (!valid) return;
    float agg = xch[wave][lane];
    size_t off = (size_t)node * 64 + lane;
    float conv = lx[off] - dinv[node] * agg;
    float vn = vp[off] - EPSL * conv;
    float xn = x[off] + EPSL * vn;
    v[off] = vn;
    x[off] = xn;
}

// ================= MLP residual (MFMA bf16x6) =================

__global__ __launch_bounds__(256) void k_mlp(
    float* __restrict__ h,
    const unsigned* __restrict__ w1_hm, const unsigned short* __restrict__ w1_l,
    const float* __restrict__ b1,
    const unsigned* __restrict__ w2_hm, const unsigned short* __restrict__ w2_l,
    const float* __restrict__ b2, int ntiles) {
    __shared__ unsigned W1hm[65 * 64], W2hm[65 * 64];
    __shared__ unsigned short W1l[65 * 64], W2l[65 * 64];
    __shared__ float B1[64], B2[64];
    __shared__ float G[4][16 * 68];
    stageP(w1_hm, w1_l, W1hm, W1l);
    stageP(w2_hm, w2_l, W2hm, W2l);
    if (threadIdx.x < 64) { B1[threadIdx.x] = b1[threadIdx.x]; B2[threadIdx.x] = b2[threadIdx.x]; }
    __syncthreads();
    int wave = threadIdx.x >> 6, lane = threadIdx.x & 63;
    int tile = blockIdx.x * 4 + wave;
    bool act = (tile < ntiles);
    int base = tile * 16;
    int m = lane & 15, quad = lane >> 4;
    short8 a1[2], a2[2], a3[2];
    float* g = G[wave];
    if (act) {
        afrag6(h + (size_t)base * 64, m, quad, 0, 64, a1[0], a2[0], a3[0]);
        afrag6(h + (size_t)base * 64, m, quad, 1, 64, a1[1], a2[1], a3[1]);
#pragma unroll
        for (int t = 0; t < 4; ++t) {
            f32x4 acc = gemm_tile6(W1hm, W1l, t, lane, a1, a2, a3, B1[t * 16 + m]);
#pragma unroll
            for (int r = 0; r < 4; ++r) {
                float tt = acc[r];
                float z = 0.7978845608028654f * (tt + 0.044715f * tt * tt * tt);
                g[(quad * 4 + r) * 68 + t * 16 + m] = 0.5f * tt * (1.f + tanhf(z));
            }
        }
    }
    __syncthreads();
    if (!act) return;
    short8 g1[2], g2[2], g3[2];
    afrag6(g, m, quad, 0, 68, g1[0], g2[0], g3[0]);
    afrag6(g, m, quad, 1, 68, g1[1], g2[1], g3[1]);
#pragma unroll
    for (int t = 0; t < 4; ++t) {
        f32x4 acc = gemm_tile6(W2hm, W2l, t, lane, g1, g2, g3, B2[t * 16 + m]);
#pragma unroll
        for (int r = 0; r < 4; ++r) {
            size_t off = (size_t)(base + quad * 4 + r) * 64 + t * 16 + m;
            h[off] = h[off] + acc[r];
        }
    }
}

// ================= final MLP + decoder fused (MLP bf16x6, dec bf16x3 terminal) =================

__global__ __launch_bounds__(256) void k_mlp_dec(
    const float* __restrict__ h,
    const unsigned* __restrict__ w1_hm, const unsigned short* __restrict__ w1_l,
    const float* __restrict__ b1,
    const unsigned* __restrict__ w2_hm, const unsigned short* __restrict__ w2_l,
    const float* __restrict__ b2,
    const unsigned* __restrict__ dec_hm, const float* __restrict__ dec_b,
    float* __restrict__ out, int ntiles) {
    __shared__ unsigned W1hm[65 * 64], W2hm[65 * 64], Wdp[33 * 64];
    __shared__ unsigned short W1l[65 * 64], W2l[65 * 64];
    __shared__ float B1[64], B2[64], Bd[32];
    __shared__ float G[4][16 * 68];
    stageP(w1_hm, w1_l, W1hm, W1l);
    stageP(w2_hm, w2_l, W2hm, W2l);
    for (int i = threadIdx.x; i < 2048; i += 256) {
        int k = i >> 5, n = i & 31;
        Wdp[k * 33 + n] = dec_hm[i];
    }
    if (threadIdx.x < 64) { B1[threadIdx.x] = b1[threadIdx.x]; B2[threadIdx.x] = b2[threadIdx.x]; }
    if (threadIdx.x < 32) Bd[threadIdx.x] = dec_b[threadIdx.x];
    __syncthreads();
    int wave = threadIdx.x >> 6, lane = threadIdx.x & 63;
    int tile = blockIdx.x * 4 + wave;
    bool act = (tile < ntiles);
    int base = tile * 16;
    int m = lane & 15, quad = lane >> 4;
    short8 a1[2], a2[2], a3[2];
    float* g = G[wave];
    if (act) {
        afrag6(h + (size_t)base * 64, m, quad, 0, 64, a1[0], a2[0], a3[0]);
        afrag6(h + (size_t)base * 64, m, quad, 1, 64, a1[1], a2[1], a3[1]);
#pragma unroll
        for (int t = 0; t < 4; ++t) {
            f32x4 acc = gemm_tile6(W1hm, W1l, t, lane, a1, a2, a3, B1[t * 16 + m]);
#pragma unroll
            for (int r = 0; r < 4; ++r) {
                float tt = acc[r];
                float z = 0.7978845608028654f * (tt + 0.044715f * tt * tt * tt);
                g[(quad * 4 + r) * 68 + t * 16 + m] = 0.5f * tt * (1.f + tanhf(z));
            }
        }
    }
    __syncthreads();
    short8 g1[2], g2[2], g3[2];
    if (act) {
        afrag6(g, m, quad, 0, 68, g1[0], g2[0], g3[0]);
        afrag6(g, m, quad, 1, 68, g1[1], g2[1], g3[1]);
    }
    __syncthreads();   // G about to be overwritten with hn
    if (act) {
#pragma unroll
        for (int t = 0; t < 4; ++t) {
            f32x4 acc = gemm_tile6(W2hm, W2l, t, lane, g1, g2, g3, B2[t * 16 + m]);
#pragma unroll
            for (int r = 0; r < 4; ++r) {
                size_t off = (size_t)(base + quad * 4 + r) * 64 + t * 16 + m;
                g[(quad * 4 + r) * 68 + t * 16 + m] = h[off] + acc[r];
            }
        }
    }
    __syncthreads();
    if (!act) return;
    short8 h1[2], h2[2], h3[2];
    afrag6(g, m, quad, 0, 68, h1[0], h2[0], h3[0]);
    afrag6(g, m, quad, 1, 68, h1[1], h2[1], h3[1]);
#pragma unroll
    for (int t = 0; t < 2; ++t) {
        int n = t * 16 + m;
        f32x4 acc = {Bd[n], Bd[n], Bd[n], Bd[n]};
#pragma unroll
        for (int hh = 0; hh < 2; ++hh) {
            short8 bh, bm;
            int k0 = hh * 32 + quad * 8;
#pragma unroll
            for (int j = 0; j < 8; ++j) {
                unsigned u = Wdp[(k0 + j) * 33 + n];
                bh[j] = (short)(u >> 16);
                bm[j] = (short)(u & 0xffffu);
            }
            acc = MFMAB(h1[hh], bh, acc);
            acc = MFMAB(h1[hh], bm, acc);
            acc = MFMAB(h2[hh], bh, acc);
        }
#pragma unroll
        for (int r = 0; r < 4; ++r)
            out[(size_t)(base + quad * 4 + r) * 32 + n] = acc[r];
    }
}

// ================= launch =================

extern "C" void kernel_launch(void* const* d_in, const int* in_sizes, int n_in,
                              void* d_out, int out_size, void* d_ws, size_t ws_size,
                              hipStream_t stream) {
    const float* x_in   = (const float*)d_in[0];
    const int*   eidx   = (const int*)d_in[1];
    const float* enc_w  = (const float*)d_in[2];
    const float* enc_b  = (const float*)d_in[3];
    const float* vel_w  = (const float*)d_in[4];
    const float* vel_b  = (const float*)d_in[5];
    const float* res_w  = (const float*)d_in[6];
    const float* res_b  = (const float*)d_in[7];
    const float* lin_w  = (const float*)d_in[8];
    const float* lin_b  = (const float*)d_in[9];
    const float* diss_w = (const float*)d_in[10];
    const float* diss_b = (const float*)d_in[11];
    const float* forc_w = (const float*)d_in[12];
    const float* forc_b = (const float*)d_in[13];
    const float* mlp_w1 = (const float*)d_in[14];
    const float* mlp_b1 = (const float*)d_in[15];
    const float* mlp_w2 = (const float*)d_in[16];
    const float* mlp_b2 = (const float*)d_in[17];
    const float* dec_w  = (const float*)d_in[18];
    const float* dec_b  = (const float*)d_in[19];
    float* out = (float*)d_out;

    const int Nn = NN, Ee = EE;
    const int* row = eidx;
    const int* col = eidx + Ee;

    char* wsp = (char*)d_ws;
    auto alloc = [&](size_t bytes) {
        char* p = wsp;
        wsp += ((bytes + 255) & ~(size_t)255);
        return p;
    };
    float*  h          = (float*)alloc((size_t)Nn * 64 * 4);
    float*  v          = (float*)alloc((size_t)Nn * 64 * 4);
    float*  lx         = (float*)alloc((size_t)Nn * 64 * 4);
    float*  vp         = (float*)alloc((size_t)Ee * 8);     // aliases CSR tmp (25.6 MB each)
    half_t* lxs        = (half_t*)alloc((size_t)Nn * 64 * 2);
    float*  aA         = (float*)alloc((size_t)Nn * 4);
    float*  bA         = (float*)alloc((size_t)Nn * 4);
    float*  dinv       = (float*)alloc((size_t)Nn * 4);
    int*    srcs_col   = (int*)alloc((size_t)Ee * 4);
    int*    dsts_row   = (int*)alloc((size_t)Ee * 4);
    int*    starts_col = (int*)alloc((size_t)(Nn + 1) * 4);
    int*    starts_row = (int*)alloc((size_t)(Nn + 1) * 4);
    int*    bc         = (int*)alloc((size_t)2 * KB * 4);
    int*    bs_col     = (int*)alloc((size_t)(KB + 1) * 4);
    int*    bs_row     = (int*)alloc((size_t)(KB + 1) * 4);
    int*    cur_col    = (int*)alloc((size_t)KB * 4);
    int*    cur_row    = (int*)alloc((size_t)KB * 4);
    unsigned*       Whm_all = (unsigned*)alloc((size_t)(DEC_OFF + 2048) * 4);
    unsigned short* Wl_all  = (unsigned short*)alloc((size_t)(DEC_OFF + 2048) * 2);
    uint2* tmp = (uint2*)vp;   // CSR build finishes before vp is first written
    int* bc_col = bc;
    int* bc_row = bc + KB;

    const int TPB = 256;
    const int gridN4 = (Nn + 3) / 4;
    const int gridS  = (Ee + 2047) / 2048;

    // ---- weight pre-split (once per launch) ----
    k_prep<<<14, TPB, 0, stream>>>(enc_w, lin_w, diss_w, forc_w, vel_w,
                                   mlp_w1, mlp_w2, dec_w, Whm_all, Wl_all);

    // ---- CSR build ----
    hipMemsetAsync(bc, 0, (size_t)2 * KB * 4, stream);
    k_hist2<<<1024, TPB, 0, stream>>>(row, col, bc_row, bc_col, Ee);
    k_scan_buckets<<<1, 512, 0, stream>>>(bc_col, bc_row, bs_col, bs_row, cur_col, cur_row);
    k_bucket_scatter<<<gridS, TPB, 0, stream>>>(col, row, cur_col, tmp, Ee);
    k_bucket_finalize<<<KB, TPB, 0, stream>>>(tmp, bs_col, starts_col, srcs_col, Nn);
    k_bucket_scatter<<<gridS, TPB, 0, stream>>>(row, col, cur_row, tmp, Ee);
    k_bucket_finalize<<<KB, TPB, 0, stream>>>(tmp, bs_row, starts_row, dsts_row, Nn);

    // ---- encoder ----
    k_enc<<<GRIDT, TPB, 0, stream>>>(x_in, Whm_all, Wl_all, enc_b, h, NTILES);

    for (int j = 0; j < 2; ++j) {
        const float* vb  = vel_b  + j * 64;
        const float* rw  = res_w  + j * 128;
        const float* rbp = res_b  + j;
        const float* lb  = lin_b  + j * 64;
        const float* db  = diss_b + j * 64;
        const float* fb  = forc_b + j * 64;
        const unsigned* lin_hm  = Whm_all + (size_t)(1 + j) * 4096;
        const unsigned short* lin_l = Wl_all + (size_t)(1 + j) * 4096;
        const unsigned* diss_hm = Whm_all + (size_t)(3 + j) * 4096;
        const unsigned short* diss_l = Wl_all + (size_t)(3 + j) * 4096;
        const unsigned* forc_hm = Whm_all + (size_t)(5 + j) * 4096;
        const unsigned short* forc_l = Wl_all + (size_t)(5 + j) * 4096;
        const unsigned* vel_hm  = Whm_all + (size_t)(7 + j) * 4096;
        const unsigned short* vel_l = Wl_all + (size_t)(7 + j) * 4096;

        for (int it = 0; it < 4; ++it) {
            k_pre_iter<<<GRIDT, TPB, 0, stream>>>(h, v, (it == 0) ? 1 : 0,
                                                  vel_hm, vel_l, vb,
                                                  lin_hm, lin_l, lb,
                                                  diss_hm, diss_l, db,
                                                  forc_hm, forc_l, fb,
                                                  rw, vp, lx, aA, bA, NTILES);
            k_deg_scale<<<gridN4, TPB, 0, stream>>>(dsts_row, starts_row, aA, bA, rbp,
                                                    lx, dinv, lxs, Nn);
            k_agg<<<gridN4, TPB, 0, stream>>>(lx, lxs, srcs_col, starts_col, dinv,
                                              aA, bA, rbp, vp, h, v, Nn);
        }

        if (j == 0)
            k_mlp<<<GRIDT, TPB, 0, stream>>>(h,
                                             Whm_all + (size_t)9 * 4096, Wl_all + (size_t)9 * 4096,
                                             mlp_b1,
                                             Whm_all + (size_t)11 * 4096, Wl_all + (size_t)11 * 4096,
                                             mlp_b2, NTILES);
        else
            k_mlp_dec<<<GRIDT, TPB, 0, stream>>>(h,
                                                 Whm_all + (size_t)10 * 4096, Wl_all + (size_t)10 * 4096,
                                                 mlp_b1 + 64,
                                                 Whm_all + (size_t)12 * 4096, Wl_all + (size_t)12 * 4096,
                                                 mlp_b2 + 64,
                                                 Whm_all + DEC_OFF, dec_b, out, NTILES);
    }
}